// Round 6
// baseline (416.442 us; speedup 1.0000x reference)
//
#include <hip/hip_runtime.h>
#include <hip/hip_bf16.h>
#include <math.h>

#define IN_CH 512
#define HID   1024
#define NH    16
#define HD    64
#define BSZ   1024
#define KVB   2064
#define NPAD  2112
#define LN_EPS 1e-5f

#define NG    176          // producer blocks in fused2 (3 tiles each = 528)
#define POOL  1024         // fused2 grid (exactly 4 blocks/CU -> all resident)

typedef _Float16 f16x8 __attribute__((ext_vector_type(8)));
typedef float f32x4  __attribute__((ext_vector_type(4)));
typedef unsigned short u16;

__device__ inline void split16(float f, u16& hi, u16& lo) {
    _Float16 h = (_Float16)f;
    _Float16 l = (_Float16)(f - (float)h);
    hi = __builtin_bit_cast(u16, h);
    lo = __builtin_bit_cast(u16, l);
}
__device__ inline u16 f2h(float f) {
    _Float16 h = (_Float16)f;
    return __builtin_bit_cast(u16, h);
}

__device__ inline void gload16(const void* g, void* l) {
    __builtin_amdgcn_global_load_lds(
        (const __attribute__((address_space(1))) unsigned int*)g,
        (__attribute__((address_space(3))) unsigned int*)l, 16, 0, 0);
}

// ------------- conversions: x -> (xh,xl) fp16; w_in -> wih; w_kvb -> wkh -----
#define QX (BSZ * IN_CH / 4)              // 131072
#define QW (HID * IN_CH / 4)              // 131072
#define QK (NPAD * HID / 4)               // 540672
#define QKVALID (KVB * HID / 4)           // 528384
#define TOTQ (QX + QW + QK)               // 802816 -> 3136 blocks

__global__ __launch_bounds__(256) void cvt_all(const float* __restrict__ x,
                                               const float* __restrict__ w_in,
                                               const float* __restrict__ w_kvb,
                                               u16* __restrict__ xh, u16* __restrict__ xl,
                                               u16* __restrict__ wih,
                                               u16* __restrict__ wkh) {
    long q = (long)blockIdx.x * 256 + threadIdx.x;
    if (q < QX) {
        float4 v = ((const float4*)x)[q];
        float f[4] = {v.x, v.y, v.z, v.w};
        ushort4 hh4, ll4;
        u16 hb[4], lb[4];
        #pragma unroll
        for (int j = 0; j < 4; ++j) split16(f[j], hb[j], lb[j]);
        hh4.x = hb[0]; hh4.y = hb[1]; hh4.z = hb[2]; hh4.w = hb[3];
        ll4.x = lb[0]; ll4.y = lb[1]; ll4.z = lb[2]; ll4.w = lb[3];
        ((ushort4*)xh)[q] = hh4;
        ((ushort4*)xl)[q] = ll4;
    } else if (q < QX + QW) {
        long lq = q - QX;
        float4 v = ((const float4*)w_in)[lq];
        ushort4 hh4;
        hh4.x = f2h(v.x); hh4.y = f2h(v.y); hh4.z = f2h(v.z); hh4.w = f2h(v.w);
        ((ushort4*)wih)[lq] = hh4;
    } else {
        long lq = q - QX - QW;
        float4 v = (lq < QKVALID) ? ((const float4*)w_kvb)[lq]
                                  : make_float4(0.f, 0.f, 0.f, 0.f);
        ushort4 hh4;
        hh4.x = f2h(v.x); hh4.y = f2h(v.y); hh4.z = f2h(v.z); hh4.w = f2h(v.w);
        ((ushort4*)wkh)[lq] = hh4;
    }
}

// ------------- fp16 2-term split GEMM, BK=64, XOR-swizzled LDS (gemm1) -------
template<int BM, int BN, int KK>
__global__ __launch_bounds__(256) void gemm_f16(const u16* __restrict__ Ah_g,
                                                const u16* __restrict__ Al_g,
                                                const u16* __restrict__ Bh_g,
                                                const float* __restrict__ bias,
                                                float* __restrict__ C,
                                                int N, int ldc) {
    constexpr int WM = BM / 2, WN = BN / 2, MF = WM / 16, NF = WN / 16;
    constexpr int UA = BM / 8;
    constexpr int U  = 2 * UA + BN / 8;
    __shared__ __align__(16) u16 Ah[2][BM][64];
    __shared__ __align__(16) u16 Al[2][BM][64];
    __shared__ __align__(16) u16 Bh[2][BN][64];

    const int t = threadIdx.x, lane = t & 63, wid = t >> 6;
    const int wm = wid >> 1, wn = wid & 1;
    const int m0 = blockIdx.y * BM, n0 = blockIdx.x * BN;

    const int seg = (lane & 7) ^ (lane >> 3);
    const int r8  = lane >> 3;

    f32x4 acc[MF][NF] = {};

    auto stage = [&](int buf, int k0) {
        #pragma unroll
        for (int it = 0; it < U / 4; ++it) {
            int u = it * 4 + wid;
            if (u < UA) {
                int row = u * 8 + r8;
                gload16(Ah_g + (size_t)(m0 + row) * KK + k0 + seg * 8,
                        &Ah[buf][u * 8][0]);
            } else if (u < 2 * UA) {
                int uu = u - UA;
                int row = uu * 8 + r8;
                gload16(Al_g + (size_t)(m0 + row) * KK + k0 + seg * 8,
                        &Al[buf][uu * 8][0]);
            } else {
                int bu = u - 2 * UA;
                int row = bu * 8 + r8;
                gload16(Bh_g + (size_t)(n0 + row) * KK + k0 + seg * 8,
                        &Bh[buf][bu * 8][0]);
            }
        }
    };

    constexpr int KT = KK / 64;
    stage(0, 0);
    __syncthreads();
    int buf = 0;
    for (int kt = 0; kt < KT; ++kt) {
        if (kt + 1 < KT) stage(buf ^ 1, (kt + 1) * 64);

        f16x8 ah[2][MF], al[2][MF], bh[2][NF];
        #pragma unroll
        for (int s = 0; s < 2; ++s) {
            #pragma unroll
            for (int mf = 0; mf < MF; ++mf) {
                int r = wm * WM + mf * 16 + (lane & 15);
                int pc = ((s << 2) | (lane >> 4)) ^ (r & 7);
                ah[s][mf] = *(const f16x8*)&Ah[buf][r][pc * 8];
                al[s][mf] = *(const f16x8*)&Al[buf][r][pc * 8];
            }
            #pragma unroll
            for (int nf = 0; nf < NF; ++nf) {
                int r = wn * WN + nf * 16 + (lane & 15);
                int pc = ((s << 2) | (lane >> 4)) ^ (r & 7);
                bh[s][nf] = *(const f16x8*)&Bh[buf][r][pc * 8];
            }
        }
        #pragma unroll
        for (int s = 0; s < 2; ++s)
            #pragma unroll
            for (int mf = 0; mf < MF; ++mf)
                #pragma unroll
                for (int nf = 0; nf < NF; ++nf) {
                    acc[mf][nf] = __builtin_amdgcn_mfma_f32_16x16x32_f16(ah[s][mf], bh[s][nf], acc[mf][nf], 0, 0, 0);
                    acc[mf][nf] = __builtin_amdgcn_mfma_f32_16x16x32_f16(al[s][mf], bh[s][nf], acc[mf][nf], 0, 0, 0);
                }
        __syncthreads();
        buf ^= 1;
    }

    #pragma unroll
    for (int mf = 0; mf < MF; ++mf)
        #pragma unroll
        for (int nf = 0; nf < NF; ++nf) {
            int col = n0 + wn * WN + nf * 16 + (lane & 15);
            if (col < N) {
                float bb = bias[col];
                #pragma unroll
                for (int r = 0; r < 4; ++r) {
                    int row = m0 + wm * WM + mf * 16 + ((lane >> 4) << 2) + r;
                    C[(size_t)row * ldc + col] = acc[mf][nf][r] + bb;
                }
            }
        }
}

// ------------- LayerNorm rows of h -> fp16 hi/lo ------------------------------
__global__ __launch_bounds__(256) void ln_rows(const float* __restrict__ h,
                                               const float* __restrict__ gamma,
                                               const float* __restrict__ beta,
                                               u16* __restrict__ hh,
                                               u16* __restrict__ hl) {
    const int row = blockIdx.x;
    const int t   = threadIdx.x;
    const float* hr = h + (size_t)row * HID;

    float4 v = *(const float4*)(hr + t * 4);
    float s  = v.x + v.y + v.z + v.w;
    float sq = v.x * v.x + v.y * v.y + v.z * v.z + v.w * v.w;

    #pragma unroll
    for (int off = 1; off < 64; off <<= 1) {
        s  += __shfl_xor(s, off);
        sq += __shfl_xor(sq, off);
    }
    __shared__ float red[8];
    const int wid = t >> 6;
    if ((t & 63) == 0) { red[wid] = s; red[4 + wid] = sq; }
    __syncthreads();
    s  = red[0] + red[1] + red[2] + red[3];
    sq = red[4] + red[5] + red[6] + red[7];

    const float mu  = s * (1.f / HID);
    const float var = sq * (1.f / HID) - mu * mu;
    const float inv = rsqrtf(var + LN_EPS);

    float4 g  = *(const float4*)(gamma + t * 4);
    float4 be = *(const float4*)(beta + t * 4);
    float o[4];
    o[0] = (v.x - mu) * inv * g.x + be.x;
    o[1] = (v.y - mu) * inv * g.y + be.y;
    o[2] = (v.z - mu) * inv * g.z + be.z;
    o[3] = (v.w - mu) * inv * g.w + be.w;

    ushort4 uh, ul;
    u16 hb[4], lb[4];
    #pragma unroll
    for (int j = 0; j < 4; ++j) split16(o[j], hb[j], lb[j]);
    uh.x = hb[0]; uh.y = hb[1]; uh.z = hb[2]; uh.w = hb[3];
    ul.x = lb[0]; ul.y = lb[1]; ul.z = lb[2]; ul.w = lb[3];
    ((ushort4*)(hh + (size_t)row * HID))[t] = uh;
    ((ushort4*)(hl + (size_t)row * HID))[t] = ul;
}

// ------------- sync-flag zeroing (ws is not re-poisoned between replays) -----
__global__ void zero_sync(unsigned* __restrict__ done) {
    if (threadIdx.x < 16) done[threadIdx.x] = 0u;
}

// ------------- tail body for one (b, head) pair -------------------------------
template<int NPRE>
__device__ __forceinline__ void tail_pair(const float* __restrict__ orow,
                                          const float* __restrict__ Wb,
                                          float* __restrict__ dWb,
                                          const int lane,
                                          const f32x4 (&pre)[8]) {
    const float kin   = orow[lane];
    const float vfull = tanhf(orow[64 + lane]);
    float t3 = 0.f;
    if (lane == 0) t3 = orow[128];
    const float lrl = __shfl(t3, 0);
    const float lr  = 1.f / (1.f + expf(-lrl));

    const int g   = lane >> 4;
    const int c16 = lane & 15;
    const f32x4* wbh = (const f32x4*)Wb;

    float rem[4] = {0.f, 0.f, 0.f, 0.f};
    #pragma unroll
    for (int tt = 0; tt < 16; ++tt) {
        const int i = 4 * tt + g;
        const float vsi = __shfl(vfull, i);
        f32x4 w4 = (tt < NPRE) ? pre[tt]
                               : __builtin_nontemporal_load(wbh + i * 16 + c16);
        rem[0] = fmaf(w4[0], vsi, rem[0]);
        rem[1] = fmaf(w4[1], vsi, rem[1]);
        rem[2] = fmaf(w4[2], vsi, rem[2]);
        rem[3] = fmaf(w4[3], vsi, rem[3]);
    }
    #pragma unroll
    for (int q = 0; q < 4; ++q) {
        rem[q] += __shfl_xor(rem[q], 16);
        rem[q] += __shfl_xor(rem[q], 32);
    }

    float L[4];
    #pragma unroll
    for (int q = 0; q < 4; ++q)
        L[q] = __shfl(kin, 4 * c16 + q) - rem[q];

    float mx = fmaxf(fmaxf(L[0], L[1]), fmaxf(L[2], L[3]));
    #pragma unroll
    for (int off = 1; off < 16; off <<= 1)
        mx = fmaxf(mx, __shfl_xor(mx, off));

    float e[4], ssum = 0.f;
    #pragma unroll
    for (int q = 0; q < 4; ++q) { e[q] = expf(L[q] - mx); ssum += e[q]; }
    #pragma unroll
    for (int off = 1; off < 16; off <<= 1)
        ssum += __shfl_xor(ssum, off);

    const float scale = lr / ssum;
    float ks[4];
    #pragma unroll
    for (int q = 0; q < 4; ++q) ks[q] = e[q] * scale;

    f32x4* obh = (f32x4*)dWb;
    #pragma unroll
    for (int tt = 0; tt < 16; ++tt) {
        const int i = 4 * tt + g;
        const float vsi = __shfl(vfull, i);
        f32x4 o;
        o[0] = vsi * ks[0]; o[1] = vsi * ks[1];
        o[2] = vsi * ks[2]; o[3] = vsi * ks[3];
        __builtin_nontemporal_store(o, obh + i * 16 + c16);
    }
}

// ------------- FUSED gemm2 + tail, producer/consumer with resident grid -------
// Grid = POOL(1024) blocks x 256 thr, __launch_bounds__(256,4) -> 4 blocks/CU,
// all blocks resident => flag spin cannot deadlock.
// Blocks 0..NG-1: 3 gemm2 tiles each (m-ascending), release done[mt]; then join
// tail pool with rank 848+bid (their own m-tiles, produced last).
// Blocks NG..1023: rank bid-NG; prefetch half of first W block, spin, stream.
__global__ __launch_bounds__(256, 4) void fused2(const u16* __restrict__ hh,
                                                 const u16* __restrict__ hl,
                                                 const u16* __restrict__ wkh,
                                                 const float* __restrict__ b_kvb,
                                                 float* __restrict__ out2,
                                                 const float* __restrict__ W,
                                                 float* __restrict__ dW,
                                                 unsigned* __restrict__ done) {
    __shared__ __align__(16) u16 Ah[2][64][32];
    __shared__ __align__(16) u16 Al[2][64][32];
    __shared__ __align__(16) u16 Bh[2][64][32];

    const int t = threadIdx.x, lane = t & 63, wid = t >> 6;
    const int bid = blockIdx.x;
    const int wm = wid >> 1, wn = wid & 1;

    if (bid < NG) {
        #pragma unroll 1
        for (int j = 0; j < 3; ++j) {
            const int idx = bid + NG * j;          // 0..527, mt ascending with j
            const int mt = idx / 33, ntl = idx % 33;
            const int m0 = mt * 64, n0 = ntl * 64;

            f32x4 acc[2][2] = {};

            auto stage = [&](int buf, int k0) {
                #pragma unroll
                for (int it = 0; it < 3; ++it) {
                    int u = it * 4 + wid;          // 0..11
                    int row16 = lane >> 2;
                    int seg = (lane & 3) ^ (row16 & 3);
                    if (u < 4) {
                        int row = u * 16 + row16;
                        gload16(hh + (size_t)(m0 + row) * HID + k0 + seg * 8,
                                &Ah[buf][u * 16][0]);
                    } else if (u < 8) {
                        int row = (u - 4) * 16 + row16;
                        gload16(hl + (size_t)(m0 + row) * HID + k0 + seg * 8,
                                &Al[buf][(u - 4) * 16][0]);
                    } else {
                        int row = (u - 8) * 16 + row16;
                        gload16(wkh + (size_t)(n0 + row) * HID + k0 + seg * 8,
                                &Bh[buf][(u - 8) * 16][0]);
                    }
                }
            };

            stage(0, 0);
            __syncthreads();
            int buf = 0;
            for (int kt = 0; kt < 32; ++kt) {
                if (kt + 1 < 32) stage(buf ^ 1, (kt + 1) * 32);

                f16x8 a_h[2], a_l[2], b_h[2];
                #pragma unroll
                for (int mf = 0; mf < 2; ++mf) {
                    int r = wm * 32 + mf * 16 + (lane & 15);
                    int pc = (lane >> 4) ^ (r & 3);
                    a_h[mf] = *(const f16x8*)&Ah[buf][r][pc * 8];
                    a_l[mf] = *(const f16x8*)&Al[buf][r][pc * 8];
                }
                #pragma unroll
                for (int nf = 0; nf < 2; ++nf) {
                    int r = wn * 32 + nf * 16 + (lane & 15);
                    int pc = (lane >> 4) ^ (r & 3);
                    b_h[nf] = *(const f16x8*)&Bh[buf][r][pc * 8];
                }
                #pragma unroll
                for (int mf = 0; mf < 2; ++mf)
                    #pragma unroll
                    for (int nf = 0; nf < 2; ++nf) {
                        acc[mf][nf] = __builtin_amdgcn_mfma_f32_16x16x32_f16(a_h[mf], b_h[nf], acc[mf][nf], 0, 0, 0);
                        acc[mf][nf] = __builtin_amdgcn_mfma_f32_16x16x32_f16(a_l[mf], b_h[nf], acc[mf][nf], 0, 0, 0);
                    }
                __syncthreads();
                buf ^= 1;
            }

            #pragma unroll
            for (int mf = 0; mf < 2; ++mf)
                #pragma unroll
                for (int nf = 0; nf < 2; ++nf) {
                    int col = n0 + wn * 32 + nf * 16 + (lane & 15);
                    if (col < KVB) {
                        float bb = b_kvb[col];
                        #pragma unroll
                        for (int r = 0; r < 4; ++r) {
                            int row = m0 + wm * 32 + mf * 16 + ((lane >> 4) << 2) + r;
                            out2[(size_t)row * KVB + col] = acc[mf][nf][r] + bb;
                        }
                    }
                }

            __threadfence();        // release: drain + L2 writeback (agent)
            __syncthreads();        // all threads' stores fenced before flag
            if (t == 0)
                __hip_atomic_fetch_add(&done[mt], 1u, __ATOMIC_RELEASE,
                                       __HIP_MEMORY_SCOPE_AGENT);
        }
    }

    // ---------------- consumer phase ----------------
    const int rank = (bid < NG) ? (POOL - NG + bid) : (bid - NG);
    const int b    = rank;                 // batch row owned by this block
    const int mtw  = b >> 6;
    const int head0 = wid * 4;
    const int g = lane >> 4, c16 = lane & 15;

    const float* Wb0  = W  + ((size_t)b * NH + head0) * (HD * HD);
    float*       dWb0 = dW + ((size_t)b * NH + head0) * (HD * HD);
    const float* orow0 = out2 + (size_t)b * KVB + head0 * (2 * HD + 1);

    // prefetch half of pair-0's W while waiting (32 VGPRs)
    f32x4 pre[8];
    #pragma unroll
    for (int tt = 0; tt < 8; ++tt) {
        int i = 4 * tt + g;
        pre[tt] = __builtin_nontemporal_load((const f32x4*)Wb0 + i * 16 + c16);
    }

    while (__hip_atomic_load(&done[mtw], __ATOMIC_RELAXED,
                             __HIP_MEMORY_SCOPE_AGENT) < 33u)
        __builtin_amdgcn_s_sleep(8);
    __threadfence();                        // acquire: invalidate caches once

    tail_pair<8>(orow0, Wb0, dWb0, lane, pre);
    #pragma unroll 1
    for (int q = 1; q < 4; ++q) {
        tail_pair<0>(orow0 + q * (2 * HD + 1),
                     Wb0  + (size_t)q * HD * HD,
                     dWb0 + (size_t)q * HD * HD, lane, pre);
    }
}

extern "C" void kernel_launch(void* const* d_in, const int* in_sizes, int n_in,
                              void* d_out, int out_size, void* d_ws, size_t ws_size,
                              hipStream_t stream) {
    const float* x     = (const float*)d_in[0];
    const float* W     = (const float*)d_in[1];
    const float* w_in  = (const float*)d_in[2];
    const float* b_in  = (const float*)d_in[3];
    const float* gamma = (const float*)d_in[4];
    const float* beta  = (const float*)d_in[5];
    const float* w_kvb = (const float*)d_in[6];
    const float* b_kvb = (const float*)d_in[7];
    float* dW = (float*)d_out;

    char* p = (char*)d_ws;
    auto carve = [&](size_t bytes) { char* r = p; p += (bytes + 255) & ~(size_t)255; return r; };
    float* h    = (float*)carve((size_t)BSZ * HID * 4);
    float* out2 = (float*)carve((size_t)BSZ * KVB * 4);
    u16* xh  = (u16*)carve((size_t)BSZ * IN_CH * 2);
    u16* xl  = (u16*)carve((size_t)BSZ * IN_CH * 2);
    u16* wih = (u16*)carve((size_t)HID * IN_CH * 2);
    u16* hh  = (u16*)carve((size_t)BSZ * HID * 2);
    u16* hl  = (u16*)carve((size_t)BSZ * HID * 2);
    u16* wkh = (u16*)carve((size_t)NPAD * HID * 2);
    unsigned* done = (unsigned*)carve(64);

    // conversions (x split fp16; w_in, w_kvb single fp16; w_kvb padded rows)
    cvt_all<<<TOTQ / 256, 256, 0, stream>>>(x, w_in, w_kvb, xh, xl, wih, wkh);

    // zero the producer/consumer flags (every call; ws not re-poisoned)
    zero_sync<<<1, 64, 0, stream>>>(done);

    // h = x @ w_in^T + b_in   (M=1024, N=1024, K=512), 32x64 tiles
    gemm_f16<32, 64, IN_CH><<<dim3(HID / 64, BSZ / 32), 256, 0, stream>>>(
        xh, xl, wih, b_in, h, HID, HID);

    // LayerNorm + fp16 hi/lo convert
    ln_rows<<<BSZ, 256, 0, stream>>>(h, gamma, beta, hh, hl);

    // fused gemm2 + tail (producer/consumer, all blocks resident)
    fused2<<<POOL, 256, 0, stream>>>(hh, hl, wkh, b_kvb, out2, W, dW, done);
}

// Round 7
// 143.200 us; speedup vs baseline: 2.9081x; 2.9081x over previous
//
#include <hip/hip_runtime.h>
#include <hip/hip_bf16.h>
#include <math.h>

#define IN_CH 512
#define HID   1024
#define NH    16
#define HD    64
#define BSZ   1024
#define KVB   2064
#define NPAD  2112
#define LN_EPS 1e-5f

typedef _Float16 f16x8 __attribute__((ext_vector_type(8)));
typedef float f32x4  __attribute__((ext_vector_type(4)));
typedef unsigned short u16;

__device__ inline void split16(float f, u16& hi, u16& lo) {
    _Float16 h = (_Float16)f;
    _Float16 l = (_Float16)(f - (float)h);
    hi = __builtin_bit_cast(u16, h);
    lo = __builtin_bit_cast(u16, l);
}
__device__ inline u16 f2h(float f) {
    _Float16 h = (_Float16)f;
    return __builtin_bit_cast(u16, h);
}

__device__ inline void gload16(const void* g, void* l) {
    __builtin_amdgcn_global_load_lds(
        (const __attribute__((address_space(1))) unsigned int*)g,
        (__attribute__((address_space(3))) unsigned int*)l, 16, 0, 0);
}

#define QX (BSZ * IN_CH / 4)              // 131072
#define QW (HID * IN_CH / 4)              // 131072
#define QK (NPAD * HID / 4)               // 540672
#define QKVALID (KVB * HID / 4)           // 528384

// ------------- D1: x -> (xh,xl) fp16 split; w_in -> fp16 ----------------------
__global__ __launch_bounds__(256) void cvt_xw(const float* __restrict__ x,
                                              const float* __restrict__ w_in,
                                              u16* __restrict__ xh, u16* __restrict__ xl,
                                              u16* __restrict__ wih) {
    long q = (long)blockIdx.x * 256 + threadIdx.x;
    if (q < QX) {
        float4 v = ((const float4*)x)[q];
        float f[4] = {v.x, v.y, v.z, v.w};
        ushort4 hh4, ll4;
        u16 hb[4], lb[4];
        #pragma unroll
        for (int j = 0; j < 4; ++j) split16(f[j], hb[j], lb[j]);
        hh4.x = hb[0]; hh4.y = hb[1]; hh4.z = hb[2]; hh4.w = hb[3];
        ll4.x = lb[0]; ll4.y = lb[1]; ll4.z = lb[2]; ll4.w = lb[3];
        ((ushort4*)xh)[q] = hh4;
        ((ushort4*)xl)[q] = ll4;
    } else {
        long lq = q - QX;
        float4 v = ((const float4*)w_in)[lq];
        ushort4 hh4;
        hh4.x = f2h(v.x); hh4.y = f2h(v.y); hh4.z = f2h(v.z); hh4.w = f2h(v.w);
        ((ushort4*)wih)[lq] = hh4;
    }
}

// ------------- D2: gemm1 (fp16 2-term split, BK=64, 128B-row XOR swizzle) -----
template<int BM, int BN, int KK>
__global__ __launch_bounds__(256) void gemm_f16(const u16* __restrict__ Ah_g,
                                                const u16* __restrict__ Al_g,
                                                const u16* __restrict__ Bh_g,
                                                const float* __restrict__ bias,
                                                float* __restrict__ C,
                                                int N, int ldc) {
    constexpr int WM = BM / 2, WN = BN / 2, MF = WM / 16, NF = WN / 16;
    constexpr int UA = BM / 8;
    constexpr int U  = 2 * UA + BN / 8;
    __shared__ __align__(16) u16 Ah[2][BM][64];
    __shared__ __align__(16) u16 Al[2][BM][64];
    __shared__ __align__(16) u16 Bh[2][BN][64];

    const int t = threadIdx.x, lane = t & 63, wid = t >> 6;
    const int wm = wid >> 1, wn = wid & 1;
    const int m0 = blockIdx.y * BM, n0 = blockIdx.x * BN;

    const int seg = (lane & 7) ^ (lane >> 3);
    const int r8  = lane >> 3;

    f32x4 acc[MF][NF] = {};

    auto stage = [&](int buf, int k0) {
        #pragma unroll
        for (int it = 0; it < U / 4; ++it) {
            int u = it * 4 + wid;
            if (u < UA) {
                int row = u * 8 + r8;
                gload16(Ah_g + (size_t)(m0 + row) * KK + k0 + seg * 8,
                        &Ah[buf][u * 8][0]);
            } else if (u < 2 * UA) {
                int uu = u - UA;
                int row = uu * 8 + r8;
                gload16(Al_g + (size_t)(m0 + row) * KK + k0 + seg * 8,
                        &Al[buf][uu * 8][0]);
            } else {
                int bu = u - 2 * UA;
                int row = bu * 8 + r8;
                gload16(Bh_g + (size_t)(n0 + row) * KK + k0 + seg * 8,
                        &Bh[buf][bu * 8][0]);
            }
        }
    };

    constexpr int KT = KK / 64;
    stage(0, 0);
    __syncthreads();
    int buf = 0;
    for (int kt = 0; kt < KT; ++kt) {
        if (kt + 1 < KT) stage(buf ^ 1, (kt + 1) * 64);

        f16x8 ah[2][MF], al[2][MF], bh[2][NF];
        #pragma unroll
        for (int s = 0; s < 2; ++s) {
            #pragma unroll
            for (int mf = 0; mf < MF; ++mf) {
                int r = wm * WM + mf * 16 + (lane & 15);
                int pc = ((s << 2) | (lane >> 4)) ^ (r & 7);
                ah[s][mf] = *(const f16x8*)&Ah[buf][r][pc * 8];
                al[s][mf] = *(const f16x8*)&Al[buf][r][pc * 8];
            }
            #pragma unroll
            for (int nf = 0; nf < NF; ++nf) {
                int r = wn * WN + nf * 16 + (lane & 15);
                int pc = ((s << 2) | (lane >> 4)) ^ (r & 7);
                bh[s][nf] = *(const f16x8*)&Bh[buf][r][pc * 8];
            }
        }
        #pragma unroll
        for (int s = 0; s < 2; ++s)
            #pragma unroll
            for (int mf = 0; mf < MF; ++mf)
                #pragma unroll
                for (int nf = 0; nf < NF; ++nf) {
                    acc[mf][nf] = __builtin_amdgcn_mfma_f32_16x16x32_f16(ah[s][mf], bh[s][nf], acc[mf][nf], 0, 0, 0);
                    acc[mf][nf] = __builtin_amdgcn_mfma_f32_16x16x32_f16(al[s][mf], bh[s][nf], acc[mf][nf], 0, 0, 0);
                }
        __syncthreads();
        buf ^= 1;
    }

    #pragma unroll
    for (int mf = 0; mf < MF; ++mf)
        #pragma unroll
        for (int nf = 0; nf < NF; ++nf) {
            int col = n0 + wn * WN + nf * 16 + (lane & 15);
            if (col < N) {
                float bb = bias[col];
                #pragma unroll
                for (int r = 0; r < 4; ++r) {
                    int row = m0 + wm * WM + mf * 16 + ((lane >> 4) << 2) + r;
                    C[(size_t)row * ldc + col] = acc[mf][nf][r] + bb;
                }
            }
        }
}

// ------------- D3: LayerNorm rows -> fp16 hi/lo  ∥  w_kvb -> fp16 -------------
__global__ __launch_bounds__(256) void ln_mix(const float* __restrict__ h,
                                              const float* __restrict__ gamma,
                                              const float* __restrict__ beta,
                                              u16* __restrict__ hh,
                                              u16* __restrict__ hl,
                                              const float* __restrict__ w_kvb,
                                              u16* __restrict__ wkh) {
    const int bid = blockIdx.x;
    const int t   = threadIdx.x;
    if (bid >= BSZ) {                      // w_kvb conversion blocks
        long lq = (long)(bid - BSZ) * 256 + t;
        float4 v = (lq < QKVALID) ? ((const float4*)w_kvb)[lq]
                                  : make_float4(0.f, 0.f, 0.f, 0.f);
        ushort4 hh4;
        hh4.x = f2h(v.x); hh4.y = f2h(v.y); hh4.z = f2h(v.z); hh4.w = f2h(v.w);
        ((ushort4*)wkh)[lq] = hh4;
        return;
    }
    const int row = bid;
    const float* hr = h + (size_t)row * HID;

    float4 v = *(const float4*)(hr + t * 4);
    float s  = v.x + v.y + v.z + v.w;
    float sq = v.x * v.x + v.y * v.y + v.z * v.z + v.w * v.w;

    #pragma unroll
    for (int off = 1; off < 64; off <<= 1) {
        s  += __shfl_xor(s, off);
        sq += __shfl_xor(sq, off);
    }
    __shared__ float red[8];
    const int wid = t >> 6;
    if ((t & 63) == 0) { red[wid] = s; red[4 + wid] = sq; }
    __syncthreads();
    s  = red[0] + red[1] + red[2] + red[3];
    sq = red[4] + red[5] + red[6] + red[7];

    const float mu  = s * (1.f / HID);
    const float var = sq * (1.f / HID) - mu * mu;
    const float inv = rsqrtf(var + LN_EPS);

    float4 g  = *(const float4*)(gamma + t * 4);
    float4 be = *(const float4*)(beta + t * 4);
    float o[4];
    o[0] = (v.x - mu) * inv * g.x + be.x;
    o[1] = (v.y - mu) * inv * g.y + be.y;
    o[2] = (v.z - mu) * inv * g.z + be.z;
    o[3] = (v.w - mu) * inv * g.w + be.w;

    ushort4 uh, ul;
    u16 hb[4], lb[4];
    #pragma unroll
    for (int j = 0; j < 4; ++j) split16(o[j], hb[j], lb[j]);
    uh.x = hb[0]; uh.y = hb[1]; uh.z = hb[2]; uh.w = hb[3];
    ul.x = lb[0]; ul.y = lb[1]; ul.z = lb[2]; ul.w = lb[3];
    ((ushort4*)(hh + (size_t)row * HID))[t] = uh;
    ((ushort4*)(hl + (size_t)row * HID))[t] = ul;
}

// ------------- tail body for one (b, head) pair -------------------------------
__device__ __forceinline__ void tail_pair(const float* __restrict__ orow,
                                          const float* __restrict__ Wb,
                                          float* __restrict__ dWb,
                                          const int lane) {
    const float kin   = orow[lane];
    const float vfull = tanhf(orow[64 + lane]);
    float t3 = 0.f;
    if (lane == 0) t3 = orow[128];
    const float lrl = __shfl(t3, 0);
    const float lr  = 1.f / (1.f + expf(-lrl));

    const int g   = lane >> 4;
    const int c16 = lane & 15;
    const f32x4* wbh = (const f32x4*)Wb;

    float rem[4] = {0.f, 0.f, 0.f, 0.f};
    #pragma unroll
    for (int tt = 0; tt < 16; ++tt) {
        const int i = 4 * tt + g;
        const float vsi = __shfl(vfull, i);
        f32x4 w4 = __builtin_nontemporal_load(wbh + i * 16 + c16);
        rem[0] = fmaf(w4[0], vsi, rem[0]);
        rem[1] = fmaf(w4[1], vsi, rem[1]);
        rem[2] = fmaf(w4[2], vsi, rem[2]);
        rem[3] = fmaf(w4[3], vsi, rem[3]);
    }
    #pragma unroll
    for (int q = 0; q < 4; ++q) {
        rem[q] += __shfl_xor(rem[q], 16);
        rem[q] += __shfl_xor(rem[q], 32);
    }

    float L[4];
    #pragma unroll
    for (int q = 0; q < 4; ++q)
        L[q] = __shfl(kin, 4 * c16 + q) - rem[q];

    float mx = fmaxf(fmaxf(L[0], L[1]), fmaxf(L[2], L[3]));
    #pragma unroll
    for (int off = 1; off < 16; off <<= 1)
        mx = fmaxf(mx, __shfl_xor(mx, off));

    float e[4], ssum = 0.f;
    #pragma unroll
    for (int q = 0; q < 4; ++q) { e[q] = expf(L[q] - mx); ssum += e[q]; }
    #pragma unroll
    for (int off = 1; off < 16; off <<= 1)
        ssum += __shfl_xor(ssum, off);

    const float scale = lr / ssum;
    float ks[4];
    #pragma unroll
    for (int q = 0; q < 4; ++q) ks[q] = e[q] * scale;

    f32x4* obh = (f32x4*)dWb;
    #pragma unroll
    for (int tt = 0; tt < 16; ++tt) {
        const int i = 4 * tt + g;
        const float vsi = __shfl(vfull, i);
        f32x4 o;
        o[0] = vsi * ks[0]; o[1] = vsi * ks[1];
        o[2] = vsi * ks[2]; o[3] = vsi * ks[3];
        __builtin_nontemporal_store(o, obh + i * 16 + c16);
    }
}

// ------------- D4/D5: heterogeneous dispatch: gemm2 tiles + tail blocks -------
// bid < nGemm : one 64x64 gemm2 tile (BK=32, 2-way-max LDS swizzle).
// bid >= nGemm: 4 tail pairs (one per wave), pair = (bid-nGemm)*4+wid+pairOff.
// No inter-block dependencies inside a dispatch.
__global__ __launch_bounds__(256) void g2t(const u16* __restrict__ hh,
                                           const u16* __restrict__ hl,
                                           const u16* __restrict__ wkh,
                                           const float* __restrict__ b_kvb,
                                           float* __restrict__ out2,
                                           const float* __restrict__ W,
                                           float* __restrict__ dW,
                                           int nGemm, int mtOff, int pairOff) {
    __shared__ __align__(16) u16 Ah[2][64][32];
    __shared__ __align__(16) u16 Al[2][64][32];
    __shared__ __align__(16) u16 Bh[2][64][32];

    const int t = threadIdx.x, lane = t & 63, wid = t >> 6;
    const int bid = blockIdx.x;

    if (bid < nGemm) {
        // XCD-chunked bijective remap within this half (nGemm % 8 == 0)
        const int w  = (bid & 7) * (nGemm >> 3) + (bid >> 3);
        const int mt = mtOff + (w & 7);
        const int nt = w >> 3;
        const int m0 = mt * 64, n0 = nt * 64;
        const int wm = wid >> 1, wn = wid & 1;

        // physical chunk pc holds logical chunk pc ^ ((row>>1)&3):
        // stage lane l -> (row_l = l>>2, pc = l&3), fetch global seg below.
        const int seg = (lane & 3) ^ ((lane >> 3) & 3);
        const int rl  = lane >> 2;

        f32x4 acc[2][2] = {};

        auto stage = [&](int buf, int k0) {
            #pragma unroll
            for (int it = 0; it < 3; ++it) {
                int u = it * 4 + wid;              // 12 wave-units
                if (u < 4) {
                    int row = u * 16 + rl;
                    gload16(hh + (size_t)(m0 + row) * HID + k0 + seg * 8,
                            &Ah[buf][u * 16][0]);
                } else if (u < 8) {
                    int row = (u - 4) * 16 + rl;
                    gload16(hl + (size_t)(m0 + row) * HID + k0 + seg * 8,
                            &Al[buf][(u - 4) * 16][0]);
                } else {
                    int row = (u - 8) * 16 + rl;
                    gload16(wkh + (size_t)(n0 + row) * HID + k0 + seg * 8,
                            &Bh[buf][(u - 8) * 16][0]);
                }
            }
        };

        stage(0, 0);
        __syncthreads();
        int buf = 0;
        for (int kt = 0; kt < HID / 32; ++kt) {
            if (kt + 1 < HID / 32) stage(buf ^ 1, (kt + 1) * 32);

            f16x8 a_h[2], a_l[2], b_h[2];
            #pragma unroll
            for (int mf = 0; mf < 2; ++mf) {
                int r = wm * 32 + mf * 16 + (lane & 15);
                int pc = (lane >> 4) ^ ((r >> 1) & 3);
                a_h[mf] = *(const f16x8*)&Ah[buf][r][pc * 8];
                a_l[mf] = *(const f16x8*)&Al[buf][r][pc * 8];
            }
            #pragma unroll
            for (int nf = 0; nf < 2; ++nf) {
                int r = wn * 32 + nf * 16 + (lane & 15);
                int pc = (lane >> 4) ^ ((r >> 1) & 3);
                b_h[nf] = *(const f16x8*)&Bh[buf][r][pc * 8];
            }
            #pragma unroll
            for (int mf = 0; mf < 2; ++mf)
                #pragma unroll
                for (int nf = 0; nf < 2; ++nf) {
                    acc[mf][nf] = __builtin_amdgcn_mfma_f32_16x16x32_f16(a_h[mf], b_h[nf], acc[mf][nf], 0, 0, 0);
                    acc[mf][nf] = __builtin_amdgcn_mfma_f32_16x16x32_f16(a_l[mf], b_h[nf], acc[mf][nf], 0, 0, 0);
                }
            __syncthreads();
            buf ^= 1;
        }

        #pragma unroll
        for (int mf = 0; mf < 2; ++mf)
            #pragma unroll
            for (int nf = 0; nf < 2; ++nf) {
                int col = n0 + wn * 32 + nf * 16 + (lane & 15);
                if (col < KVB) {
                    float bb = b_kvb[col];
                    #pragma unroll
                    for (int r = 0; r < 4; ++r) {
                        int row = m0 + wm * 32 + mf * 16 + ((lane >> 4) << 2) + r;
                        out2[(size_t)row * KVB + col] = acc[mf][nf][r] + bb;
                    }
                }
            }
    } else {
        const int pair = (bid - nGemm) * 4 + wid + pairOff;
        const int b    = pair >> 4;
        const int head = pair & 15;
        tail_pair(out2 + (size_t)b * KVB + head * (2 * HD + 1),
                  W  + (size_t)pair * (HD * HD),
                  dW + (size_t)pair * (HD * HD), lane);
    }
}

// ------------- D6: pure tail (max occupancy, no LDS) --------------------------
__global__ __launch_bounds__(256) void oja_tail(const float* __restrict__ out2,
                                                const float* __restrict__ W,
                                                float* __restrict__ dW,
                                                int pairOff) {
    const int lane = threadIdx.x & 63;
    const int wid  = threadIdx.x >> 6;
    const int pair = blockIdx.x * 4 + wid + pairOff;
    const int b    = pair >> 4;
    const int head = pair & 15;
    tail_pair(out2 + (size_t)b * KVB + head * (2 * HD + 1),
              W  + (size_t)pair * (HD * HD),
              dW + (size_t)pair * (HD * HD), lane);
}

extern "C" void kernel_launch(void* const* d_in, const int* in_sizes, int n_in,
                              void* d_out, int out_size, void* d_ws, size_t ws_size,
                              hipStream_t stream) {
    const float* x     = (const float*)d_in[0];
    const float* W     = (const float*)d_in[1];
    const float* w_in  = (const float*)d_in[2];
    const float* b_in  = (const float*)d_in[3];
    const float* gamma = (const float*)d_in[4];
    const float* beta  = (const float*)d_in[5];
    const float* w_kvb = (const float*)d_in[6];
    const float* b_kvb = (const float*)d_in[7];
    float* dW = (float*)d_out;

    char* p = (char*)d_ws;
    auto carve = [&](size_t bytes) { char* r = p; p += (bytes + 255) & ~(size_t)255; return r; };
    float* h    = (float*)carve((size_t)BSZ * HID * 4);
    float* out2 = (float*)carve((size_t)BSZ * KVB * 4);
    u16* xh  = (u16*)carve((size_t)BSZ * IN_CH * 2);
    u16* xl  = (u16*)carve((size_t)BSZ * IN_CH * 2);
    u16* wih = (u16*)carve((size_t)HID * IN_CH * 2);
    u16* hh  = (u16*)carve((size_t)BSZ * HID * 2);
    u16* hl  = (u16*)carve((size_t)BSZ * HID * 2);
    u16* wkh = (u16*)carve((size_t)NPAD * HID * 2);

    // D1: x split + w_in convert   (QX+QW = 262144 quads -> 1024 blocks)
    cvt_xw<<<(QX + QW) / 256, 256, 0, stream>>>(x, w_in, xh, xl, wih);

    // D2: h = x @ w_in^T + b_in   (M=1024, N=1024, K=512)
    gemm_f16<32, 64, IN_CH><<<dim3(HID / 64, BSZ / 32), 256, 0, stream>>>(
        xh, xl, wih, b_in, h, HID, HID);

    // D3: LayerNorm (1024 blocks)  ∥  w_kvb fp16 convert (2112 blocks)
    ln_mix<<<BSZ + QK / 256, 256, 0, stream>>>(h, gamma, beta, hh, hl, w_kvb, wkh);

    // D4: gemm2 on batch rows 0..511  (8 m-tiles x 33 n-tiles = 264 blocks)
    g2t<<<264, 256, 0, stream>>>(hh, hl, wkh, b_kvb, out2, W, dW, 264, 0, 0);

    // D5: gemm2 rows 512..1023 (264)  ∥  tail pairs 0..8191 (2048 blocks)
    g2t<<<264 + 2048, 256, 0, stream>>>(hh, hl, wkh, b_kvb, out2, W, dW, 264, 8, 0);

    // D6: tail pairs 8192..16383
    oja_tail<<<2048, 256, 0, stream>>>(out2, W, dW, 8192);
}

// Round 8
// 132.838 us; speedup vs baseline: 3.1350x; 1.0780x over previous
//
#include <hip/hip_runtime.h>
#include <hip/hip_bf16.h>
#include <math.h>

#define IN_CH 512
#define HID   1024
#define NH    16
#define HD    64
#define BSZ   1024
#define KVB   2064
#define NPAD  2112
#define LN_EPS 1e-5f

typedef _Float16 f16x8 __attribute__((ext_vector_type(8)));
typedef float f32x4  __attribute__((ext_vector_type(4)));
typedef unsigned short u16;

__device__ inline void split16(float f, u16& hi, u16& lo) {
    _Float16 h = (_Float16)f;
    _Float16 l = (_Float16)(f - (float)h);
    hi = __builtin_bit_cast(u16, h);
    lo = __builtin_bit_cast(u16, l);
}
__device__ inline u16 f2h(float f) {
    _Float16 h = (_Float16)f;
    return __builtin_bit_cast(u16, h);
}

__device__ inline void gload16(const void* g, void* l) {
    __builtin_amdgcn_global_load_lds(
        (const __attribute__((address_space(1))) unsigned int*)g,
        (__attribute__((address_space(3))) unsigned int*)l, 16, 0, 0);
}

#define QX (BSZ * IN_CH / 4)              // 131072
#define QW (HID * IN_CH / 4)              // 131072
#define QK (NPAD * HID / 4)               // 540672
#define QKVALID (KVB * HID / 4)           // 528384

// ------------- D1: x -> (xh,xl) fp16 split; w_in -> fp16 ----------------------
__global__ __launch_bounds__(256) void cvt_xw(const float* __restrict__ x,
                                              const float* __restrict__ w_in,
                                              u16* __restrict__ xh, u16* __restrict__ xl,
                                              u16* __restrict__ wih) {
    long q = (long)blockIdx.x * 256 + threadIdx.x;
    if (q < QX) {
        float4 v = ((const float4*)x)[q];
        float f[4] = {v.x, v.y, v.z, v.w};
        ushort4 hh4, ll4;
        u16 hb[4], lb[4];
        #pragma unroll
        for (int j = 0; j < 4; ++j) split16(f[j], hb[j], lb[j]);
        hh4.x = hb[0]; hh4.y = hb[1]; hh4.z = hb[2]; hh4.w = hb[3];
        ll4.x = lb[0]; ll4.y = lb[1]; ll4.z = lb[2]; ll4.w = lb[3];
        ((ushort4*)xh)[q] = hh4;
        ((ushort4*)xl)[q] = ll4;
    } else {
        long lq = q - QX;
        float4 v = ((const float4*)w_in)[lq];
        ushort4 hh4;
        hh4.x = f2h(v.x); hh4.y = f2h(v.y); hh4.z = f2h(v.z); hh4.w = f2h(v.w);
        ((ushort4*)wih)[lq] = hh4;
    }
}

// ------------- D2: gemm1 (fp16, A split 2-term, BK=64, XOR swizzle) -----------
template<int BM, int BN, int KK>
__global__ __launch_bounds__(256) void gemm_f16s(const u16* __restrict__ Ah_g,
                                                 const u16* __restrict__ Al_g,
                                                 const u16* __restrict__ Bh_g,
                                                 const float* __restrict__ bias,
                                                 float* __restrict__ C,
                                                 int N, int ldc) {
    constexpr int WM = BM / 2, WN = BN / 2, MF = WM / 16, NF = WN / 16;
    constexpr int UA = BM / 8;
    constexpr int U  = 2 * UA + BN / 8;
    __shared__ __align__(16) u16 Ah[2][BM][64];
    __shared__ __align__(16) u16 Al[2][BM][64];
    __shared__ __align__(16) u16 Bh[2][BN][64];

    const int t = threadIdx.x, lane = t & 63, wid = t >> 6;
    const int wm = wid >> 1, wn = wid & 1;
    const int m0 = blockIdx.y * BM, n0 = blockIdx.x * BN;

    const int seg = (lane & 7) ^ (lane >> 3);
    const int r8  = lane >> 3;

    f32x4 acc[MF][NF] = {};

    auto stage = [&](int buf, int k0) {
        #pragma unroll
        for (int it = 0; it < U / 4; ++it) {
            int u = it * 4 + wid;
            if (u < UA) {
                int row = u * 8 + r8;
                gload16(Ah_g + (size_t)(m0 + row) * KK + k0 + seg * 8,
                        &Ah[buf][u * 8][0]);
            } else if (u < 2 * UA) {
                int uu = u - UA;
                int row = uu * 8 + r8;
                gload16(Al_g + (size_t)(m0 + row) * KK + k0 + seg * 8,
                        &Al[buf][uu * 8][0]);
            } else {
                int bu = u - 2 * UA;
                int row = bu * 8 + r8;
                gload16(Bh_g + (size_t)(n0 + row) * KK + k0 + seg * 8,
                        &Bh[buf][bu * 8][0]);
            }
        }
    };

    constexpr int KT = KK / 64;
    stage(0, 0);
    __syncthreads();
    int buf = 0;
    for (int kt = 0; kt < KT; ++kt) {
        if (kt + 1 < KT) stage(buf ^ 1, (kt + 1) * 64);

        f16x8 ah[2][MF], al[2][MF], bh[2][NF];
        #pragma unroll
        for (int s = 0; s < 2; ++s) {
            #pragma unroll
            for (int mf = 0; mf < MF; ++mf) {
                int r = wm * WM + mf * 16 + (lane & 15);
                int pc = ((s << 2) | (lane >> 4)) ^ (r & 7);
                ah[s][mf] = *(const f16x8*)&Ah[buf][r][pc * 8];
                al[s][mf] = *(const f16x8*)&Al[buf][r][pc * 8];
            }
            #pragma unroll
            for (int nf = 0; nf < NF; ++nf) {
                int r = wn * WN + nf * 16 + (lane & 15);
                int pc = ((s << 2) | (lane >> 4)) ^ (r & 7);
                bh[s][nf] = *(const f16x8*)&Bh[buf][r][pc * 8];
            }
        }
        #pragma unroll
        for (int s = 0; s < 2; ++s)
            #pragma unroll
            for (int mf = 0; mf < MF; ++mf)
                #pragma unroll
                for (int nf = 0; nf < NF; ++nf) {
                    acc[mf][nf] = __builtin_amdgcn_mfma_f32_16x16x32_f16(ah[s][mf], bh[s][nf], acc[mf][nf], 0, 0, 0);
                    acc[mf][nf] = __builtin_amdgcn_mfma_f32_16x16x32_f16(al[s][mf], bh[s][nf], acc[mf][nf], 0, 0, 0);
                }
        __syncthreads();
        buf ^= 1;
    }

    #pragma unroll
    for (int mf = 0; mf < MF; ++mf)
        #pragma unroll
        for (int nf = 0; nf < NF; ++nf) {
            int col = n0 + wn * WN + nf * 16 + (lane & 15);
            if (col < N) {
                float bb = bias[col];
                #pragma unroll
                for (int r = 0; r < 4; ++r) {
                    int row = m0 + wm * WM + mf * 16 + ((lane >> 4) << 2) + r;
                    C[(size_t)row * ldc + col] = acc[mf][nf][r] + bb;
                }
            }
        }
}

// ------------- D4: gemm2 (pure single fp16, BK=64, XOR swizzle, XCD remap) ----
template<int BM, int BN, int KK>
__global__ __launch_bounds__(256) void gemm_f16x(const u16* __restrict__ Ah_g,
                                                 const u16* __restrict__ Bh_g,
                                                 const float* __restrict__ bias,
                                                 float* __restrict__ C,
                                                 int N, int ldc) {
    constexpr int WM = BM / 2, WN = BN / 2, MF = WM / 16, NF = WN / 16;
    constexpr int UA = BM / 8;
    constexpr int U  = UA + BN / 8;
    __shared__ __align__(16) u16 Ah[2][BM][64];
    __shared__ __align__(16) u16 Bh[2][BN][64];

    const int t = threadIdx.x, lane = t & 63, wid = t >> 6;
    const int wm = wid >> 1, wn = wid & 1;

    // XCD-chunked bijective remap (grid % 8 == 0)
    const int bid = blockIdx.x, nwg = gridDim.x;
    const int w = (bid & 7) * (nwg >> 3) + (bid >> 3);
    const int mt = w & (BSZ / BM - 1);
    const int nt = w / (BSZ / BM);
    const int m0 = mt * BM, n0 = nt * BN;

    const int seg = (lane & 7) ^ (lane >> 3);
    const int r8  = lane >> 3;

    f32x4 acc[MF][NF] = {};

    auto stage = [&](int buf, int k0) {
        #pragma unroll
        for (int it = 0; it < U / 4; ++it) {
            int u = it * 4 + wid;
            if (u < UA) {
                int row = u * 8 + r8;
                gload16(Ah_g + (size_t)(m0 + row) * KK + k0 + seg * 8,
                        &Ah[buf][u * 8][0]);
            } else {
                int bu = u - UA;
                int row = bu * 8 + r8;
                gload16(Bh_g + (size_t)(n0 + row) * KK + k0 + seg * 8,
                        &Bh[buf][bu * 8][0]);
            }
        }
    };

    constexpr int KT = KK / 64;
    stage(0, 0);
    __syncthreads();
    int buf = 0;
    for (int kt = 0; kt < KT; ++kt) {
        if (kt + 1 < KT) stage(buf ^ 1, (kt + 1) * 64);

        f16x8 ah[2][MF], bh[2][NF];
        #pragma unroll
        for (int s = 0; s < 2; ++s) {
            #pragma unroll
            for (int mf = 0; mf < MF; ++mf) {
                int r = wm * WM + mf * 16 + (lane & 15);
                int pc = ((s << 2) | (lane >> 4)) ^ (r & 7);
                ah[s][mf] = *(const f16x8*)&Ah[buf][r][pc * 8];
            }
            #pragma unroll
            for (int nf = 0; nf < NF; ++nf) {
                int r = wn * WN + nf * 16 + (lane & 15);
                int pc = ((s << 2) | (lane >> 4)) ^ (r & 7);
                bh[s][nf] = *(const f16x8*)&Bh[buf][r][pc * 8];
            }
        }
        #pragma unroll
        for (int s = 0; s < 2; ++s)
            #pragma unroll
            for (int mf = 0; mf < MF; ++mf)
                #pragma unroll
                for (int nf = 0; nf < NF; ++nf)
                    acc[mf][nf] = __builtin_amdgcn_mfma_f32_16x16x32_f16(ah[s][mf], bh[s][nf], acc[mf][nf], 0, 0, 0);
        __syncthreads();
        buf ^= 1;
    }

    #pragma unroll
    for (int mf = 0; mf < MF; ++mf)
        #pragma unroll
        for (int nf = 0; nf < NF; ++nf) {
            int col = n0 + wn * WN + nf * 16 + (lane & 15);
            if (col < N) {
                float bb = bias[col];
                #pragma unroll
                for (int r = 0; r < 4; ++r) {
                    int row = m0 + wm * WM + mf * 16 + ((lane >> 4) << 2) + r;
                    C[(size_t)row * ldc + col] = acc[mf][nf][r] + bb;
                }
            }
        }
}

// ------------- D3: LayerNorm rows -> fp16 (single)  ∥  w_kvb -> fp16 ----------
__global__ __launch_bounds__(256) void ln_mix(const float* __restrict__ h,
                                              const float* __restrict__ gamma,
                                              const float* __restrict__ beta,
                                              u16* __restrict__ hh,
                                              const float* __restrict__ w_kvb,
                                              u16* __restrict__ wkh) {
    const int bid = blockIdx.x;
    const int t   = threadIdx.x;
    if (bid >= BSZ) {                      // w_kvb conversion blocks
        long lq = (long)(bid - BSZ) * 256 + t;
        float4 v = (lq < QKVALID) ? ((const float4*)w_kvb)[lq]
                                  : make_float4(0.f, 0.f, 0.f, 0.f);
        ushort4 hh4;
        hh4.x = f2h(v.x); hh4.y = f2h(v.y); hh4.z = f2h(v.z); hh4.w = f2h(v.w);
        ((ushort4*)wkh)[lq] = hh4;
        return;
    }
    const int row = bid;
    const float* hr = h + (size_t)row * HID;

    float4 v = *(const float4*)(hr + t * 4);
    float s  = v.x + v.y + v.z + v.w;
    float sq = v.x * v.x + v.y * v.y + v.z * v.z + v.w * v.w;

    #pragma unroll
    for (int off = 1; off < 64; off <<= 1) {
        s  += __shfl_xor(s, off);
        sq += __shfl_xor(sq, off);
    }
    __shared__ float red[8];
    const int wid = t >> 6;
    if ((t & 63) == 0) { red[wid] = s; red[4 + wid] = sq; }
    __syncthreads();
    s  = red[0] + red[1] + red[2] + red[3];
    sq = red[4] + red[5] + red[6] + red[7];

    const float mu  = s * (1.f / HID);
    const float var = sq * (1.f / HID) - mu * mu;
    const float inv = rsqrtf(var + LN_EPS);

    float4 g  = *(const float4*)(gamma + t * 4);
    float4 be = *(const float4*)(beta + t * 4);
    float o[4];
    o[0] = (v.x - mu) * inv * g.x + be.x;
    o[1] = (v.y - mu) * inv * g.y + be.y;
    o[2] = (v.z - mu) * inv * g.z + be.z;
    o[3] = (v.w - mu) * inv * g.w + be.w;

    ushort4 uh;
    uh.x = f2h(o[0]); uh.y = f2h(o[1]); uh.z = f2h(o[2]); uh.w = f2h(o[3]);
    ((ushort4*)(hh + (size_t)row * HID))[t] = uh;
}

// ------------- D5: tail, one wave per (b, head); nontemporal W/dW -------------
__global__ __launch_bounds__(256) void oja_tail(const float* __restrict__ out2,
                                                const float* __restrict__ W,
                                                float* __restrict__ dW) {
    const int lane = threadIdx.x & 63;
    const int wid  = threadIdx.x >> 6;
    const int pair = blockIdx.x * 4 + wid;      // b*16 + head
    const int b    = pair >> 4;
    const int head = pair & 15;

    const float* orow = out2 + (size_t)b * KVB + head * (2 * HD + 1);

    const float kin   = orow[lane];
    const float vfull = tanhf(orow[64 + lane]);
    float t3 = 0.f;
    if (lane == 0) t3 = orow[128];
    const float lrl = __shfl(t3, 0);
    const float lr  = 1.f / (1.f + expf(-lrl));

    const int g   = lane >> 4;
    const int c16 = lane & 15;

    const f32x4* wbh = (const f32x4*)(W + (size_t)pair * (HD * HD));

    float rem[4] = {0.f, 0.f, 0.f, 0.f};
    #pragma unroll
    for (int tt = 0; tt < 16; ++tt) {
        const int i = 4 * tt + g;
        const float vsi = __shfl(vfull, i);
        f32x4 w4 = __builtin_nontemporal_load(wbh + i * 16 + c16);
        rem[0] = fmaf(w4[0], vsi, rem[0]);
        rem[1] = fmaf(w4[1], vsi, rem[1]);
        rem[2] = fmaf(w4[2], vsi, rem[2]);
        rem[3] = fmaf(w4[3], vsi, rem[3]);
    }
    #pragma unroll
    for (int q = 0; q < 4; ++q) {
        rem[q] += __shfl_xor(rem[q], 16);
        rem[q] += __shfl_xor(rem[q], 32);
    }

    float L[4];
    #pragma unroll
    for (int q = 0; q < 4; ++q)
        L[q] = __shfl(kin, 4 * c16 + q) - rem[q];

    float mx = fmaxf(fmaxf(L[0], L[1]), fmaxf(L[2], L[3]));
    #pragma unroll
    for (int off = 1; off < 16; off <<= 1)
        mx = fmaxf(mx, __shfl_xor(mx, off));

    float e[4], ssum = 0.f;
    #pragma unroll
    for (int q = 0; q < 4; ++q) { e[q] = expf(L[q] - mx); ssum += e[q]; }
    #pragma unroll
    for (int off = 1; off < 16; off <<= 1)
        ssum += __shfl_xor(ssum, off);

    const float scale = lr / ssum;
    float ks[4];
    #pragma unroll
    for (int q = 0; q < 4; ++q) ks[q] = e[q] * scale;

    f32x4* obh = (f32x4*)(dW + (size_t)pair * (HD * HD));
    #pragma unroll
    for (int tt = 0; tt < 16; ++tt) {
        const int i = 4 * tt + g;
        const float vsi = __shfl(vfull, i);
        f32x4 o;
        o[0] = vsi * ks[0]; o[1] = vsi * ks[1];
        o[2] = vsi * ks[2]; o[3] = vsi * ks[3];
        __builtin_nontemporal_store(o, obh + i * 16 + c16);
    }
}

extern "C" void kernel_launch(void* const* d_in, const int* in_sizes, int n_in,
                              void* d_out, int out_size, void* d_ws, size_t ws_size,
                              hipStream_t stream) {
    const float* x     = (const float*)d_in[0];
    const float* W     = (const float*)d_in[1];
    const float* w_in  = (const float*)d_in[2];
    const float* b_in  = (const float*)d_in[3];
    const float* gamma = (const float*)d_in[4];
    const float* beta  = (const float*)d_in[5];
    const float* w_kvb = (const float*)d_in[6];
    const float* b_kvb = (const float*)d_in[7];
    float* dW = (float*)d_out;

    char* p = (char*)d_ws;
    auto carve = [&](size_t bytes) { char* r = p; p += (bytes + 255) & ~(size_t)255; return r; };
    float* h    = (float*)carve((size_t)BSZ * HID * 4);
    float* out2 = (float*)carve((size_t)BSZ * KVB * 4);
    u16* xh  = (u16*)carve((size_t)BSZ * IN_CH * 2);
    u16* xl  = (u16*)carve((size_t)BSZ * IN_CH * 2);
    u16* wih = (u16*)carve((size_t)HID * IN_CH * 2);
    u16* hh  = (u16*)carve((size_t)BSZ * HID * 2);
    u16* wkh = (u16*)carve((size_t)NPAD * HID * 2);

    // D1: x split + w_in convert  (1024 blocks)
    cvt_xw<<<(QX + QW) / 256, 256, 0, stream>>>(x, w_in, xh, xl, wih);

    // D2: h = x @ w_in^T + b_in   (M=1024, N=1024, K=512), A-split fp16
    gemm_f16s<32, 64, IN_CH><<<dim3(HID / 64, BSZ / 32), 256, 0, stream>>>(
        xh, xl, wih, b_in, h, HID, HID);

    // D3: LayerNorm -> fp16 (1024 blocks)  ∥  w_kvb fp16 convert (2112 blocks)
    ln_mix<<<BSZ + QK / 256, 256, 0, stream>>>(h, gamma, beta, hh, w_kvb, wkh);

    // D4: out2 = h @ w_kvb^T + b_kvb  (single fp16; 528 blocks, XCD swizzle)
    gemm_f16x<64, 64, HID><<<(NPAD / 64) * (BSZ / 64), 256, 0, stream>>>(
        hh, wkh, b_kvb, out2, KVB, KVB);

    // D5: tail
    oja_tail<<<(BSZ * NH) / 4, 256, 0, stream>>>(out2, W, dW);
}